// Round 3
// baseline (1768.147 us; speedup 1.0000x reference)
//
#include <hip/hip_runtime.h>
#include <hip/hip_bf16.h>
#include <math.h>

// ---------------------------------------------------------------------------
// 3-layer GAT (heads=1, PyG semantics, self-loops appended after E edges).
// Runtime dtype sniffing: flags[0]=x is bf16, flags[1]=weights are bf16,
// flags[2]=edge_index is int64. Output dtype follows flags[0].
// f32 internal math throughout.
// ws layout (floats): A[n*64] | B[n*64] | ssrc[n] | sdst[n] | m[n] | denom[n]
//                     | ev[E+n] | flags[4 ints]
// ---------------------------------------------------------------------------

__device__ __forceinline__ float loadf(const void* p, long i, int bf) {
  return bf ? __bfloat162float(((const __hip_bfloat16*)p)[i])
            : ((const float*)p)[i];
}

__global__ void sniff(const unsigned int* __restrict__ x,
                      const unsigned int* __restrict__ w,
                      const int* __restrict__ ei, int* __restrict__ flags) {
  if (threadIdx.x == 0 && blockIdx.x == 0) {
    int cx = 0, cw = 0;
    for (int i = 0; i < 256; ++i) {
      unsigned ex = (x[i] >> 7) & 0xFFu;           // low-halfword exponent field
      cx += (ex >= 100u && ex <= 140u);
      unsigned ew = (w[i] >> 7) & 0xFFu;
      cw += (ew >= 100u && ew <= 140u);
    }
    flags[0] = (cx > 128) ? 1 : 0;  // bf16-packed x
    flags[1] = (cw > 128) ? 1 : 0;  // bf16-packed weights
    int any = 0;
    for (int i = 1; i < 64; i += 2) any |= ei[i];
    flags[2] = (any == 0) ? 1 : 0;  // int64 edge_index
  }
}

__device__ __forceinline__ void load_edge(const int* __restrict__ ei, int E,
                                          int e, int is64, int n, int& s,
                                          int& d) {
  if (e < E) {
    if (is64) {
      s = ei[2 * e];
      d = ei[2 * (E + e)];
    } else {
      s = ei[e];
      d = ei[E + e];
    }
    s = min(max(s, 0), n - 1);
    d = min(max(d, 0), n - 1);
  } else {
    s = d = e - E;  // self-loop
  }
}

template <int F_IN, int F_OUT>
__global__ void gemm_att(const void* __restrict__ x, int x_dyn,
                         const void* __restrict__ W,
                         const void* __restrict__ a_src,
                         const void* __restrict__ a_dst,
                         const int* __restrict__ flags,
                         float* __restrict__ h, float* __restrict__ s_src,
                         float* __restrict__ s_dst, int n) {
  const int xbf = x_dyn ? flags[0] : 0;
  const int wbf = flags[1];
  const int wave = threadIdx.x >> 6;
  const int lane = threadIdx.x & 63;
  const int node = blockIdx.x * 4 + wave;
  if (node >= n) return;

  constexpr int XR = F_IN / 64;
  float xr[XR];
#pragma unroll
  for (int i = 0; i < XR; ++i)
    xr[i] = loadf(x, (long)node * F_IN + i * 64 + lane, xbf);

  float acc = 0.f;
#pragma unroll
  for (int k = 0; k < F_IN; ++k) {
    float xk = __shfl(xr[k >> 6], k & 63);
    float wk = (lane < F_OUT) ? loadf(W, (long)k * F_OUT + lane, wbf) : 0.f;
    acc = fmaf(xk, wk, acc);
  }

  if (lane < F_OUT) h[(long)node * F_OUT + lane] = acc;

  float pa = (lane < F_OUT) ? acc * loadf(a_src, lane, wbf) : 0.f;
  float pb = (lane < F_OUT) ? acc * loadf(a_dst, lane, wbf) : 0.f;
#pragma unroll
  for (int off = 32; off > 0; off >>= 1) {
    pa += __shfl_xor(pa, off);
    pb += __shfl_xor(pb, off);
  }
  if (lane == 0) {
    s_src[node] = pa;
    s_dst[node] = pb;
  }
}

__global__ void init_layer(float* __restrict__ agg, float* __restrict__ m,
                           float* __restrict__ denom, int n, int f_out) {
  const int i = blockIdx.x * blockDim.x + threadIdx.x;
  if (i < n * f_out) agg[i] = 0.f;
  if (i < n) {
    m[i] = __int_as_float(0xFF800000);  // -inf
    denom[i] = 0.f;
  }
}

__global__ void edge_score(const int* __restrict__ ei, int E, int n,
                           const int* __restrict__ flags,
                           const float* __restrict__ s_src,
                           const float* __restrict__ s_dst,
                           float* __restrict__ ev, float* __restrict__ m) {
  const int e = blockIdx.x * blockDim.x + threadIdx.x;
  if (e >= E + n) return;
  const int is64 = flags[2];
  int s, d;
  load_edge(ei, E, e, is64, n, s, d);
  float v = s_src[s] + s_dst[d];
  v = v > 0.f ? v : 0.2f * v;
  ev[e] = v;
  // float atomic-max via ordered-int trick (m pre-set to -inf)
  if (v >= 0.f)
    atomicMax((int*)(m + d), __float_as_int(v));
  else
    atomicMin((unsigned int*)(m + d), __float_as_uint(v));
}

__global__ void edge_exp(const int* __restrict__ ei, int E, int n,
                         const int* __restrict__ flags,
                         const float* __restrict__ m, float* __restrict__ ev,
                         float* __restrict__ denom) {
  const int e = blockIdx.x * blockDim.x + threadIdx.x;
  if (e >= E + n) return;
  const int is64 = flags[2];
  int s, d;
  load_edge(ei, E, e, is64, n, s, d);
  const float w = expf(ev[e] - m[d]);
  ev[e] = w;
  atomicAdd(denom + d, w);
}

template <int F_OUT>
__global__ void edge_aggr(const int* __restrict__ ei, int E, int n,
                          const int* __restrict__ flags,
                          const float* __restrict__ ev,
                          const float* __restrict__ denom,
                          const float* __restrict__ h, float* __restrict__ agg) {
  const int wave = threadIdx.x >> 6;
  const int lane = threadIdx.x & 63;
  const int e = blockIdx.x * 4 + wave;
  if (e >= E + n) return;
  const int is64 = flags[2];
  int s, d;
  load_edge(ei, E, e, is64, n, s, d);
  const float alpha = ev[e] / (denom[d] + 1e-16f);
  if (lane < F_OUT)
    atomicAdd(agg + (long)d * F_OUT + lane, alpha * h[(long)s * F_OUT + lane]);
}

// in-place: agg := gelu(agg + b)
template <int F_OUT>
__global__ void finalize_gelu(float* __restrict__ agg,
                              const void* __restrict__ b,
                              const int* __restrict__ flags, int n) {
  const int i = blockIdx.x * blockDim.x + threadIdx.x;
  if (i >= n * F_OUT) return;
  float v = agg[i] + loadf(b, i % F_OUT, flags[1]);
  v = 0.5f * v * (1.0f + erff(v * 0.70710678118654752f));
  agg[i] = v;
}

template <int F_OUT>
__global__ void finalize_out(const float* __restrict__ agg,
                             const void* __restrict__ b,
                             const int* __restrict__ flags,
                             void* __restrict__ out, int n) {
  const int i = blockIdx.x * blockDim.x + threadIdx.x;
  if (i >= n * F_OUT) return;
  float v = agg[i] + loadf(b, i % F_OUT, flags[1]);
  if (flags[0])
    ((__hip_bfloat16*)out)[i] = __float2bfloat16(v);
  else
    ((float*)out)[i] = v;
}

extern "C" void kernel_launch(void* const* d_in, const int* in_sizes, int n_in,
                              void* d_out, int out_size, void* d_ws,
                              size_t ws_size, hipStream_t stream) {
  const void* x = d_in[0];
  const int* ei = (const int*)d_in[1];
  const void* W1 = d_in[2];
  const void* as1 = d_in[3];
  const void* ad1 = d_in[4];
  const void* b1 = d_in[5];
  const void* W2 = d_in[6];
  const void* as2 = d_in[7];
  const void* ad2 = d_in[8];
  const void* b2 = d_in[9];
  const void* W3 = d_in[10];
  const void* as3 = d_in[11];
  const void* ad3 = d_in[12];
  const void* b3 = d_in[13];

  const int n = in_sizes[0] / 128;  // 50000
  const int E = in_sizes[1] / 2;    // 800000
  const int total = E + n;

  const size_t need =
      ((size_t)n * 64 * 2 + 4 * (size_t)n + (size_t)total) * 4 + 64;
  if (ws_size < need) return;

  float* A = (float*)d_ws;        // h
  float* B = A + (size_t)n * 64;  // agg / next-layer input
  float* ssrc = B + (size_t)n * 64;
  float* sdst = ssrc + n;
  float* m = sdst + n;
  float* denom = m + n;
  float* ev = denom + n;
  int* flags = (int*)(ev + total);

  const int gemm_blocks = (n + 3) / 4;
  const int eb1 = (total + 255) / 256;
  const int eb4 = (total + 3) / 4;
  const int nb64 = (n * 64 + 255) / 256;
  const int nb40 = (n * 40 + 255) / 256;

  sniff<<<1, 64, 0, stream>>>((const unsigned int*)x, (const unsigned int*)W1,
                              ei, flags);

  // ---- Layer 1: 128 -> 64, GELU ----
  gemm_att<128, 64><<<gemm_blocks, 256, 0, stream>>>(x, 1, W1, as1, ad1, flags,
                                                     A, ssrc, sdst, n);
  init_layer<<<nb64, 256, 0, stream>>>(B, m, denom, n, 64);
  edge_score<<<eb1, 256, 0, stream>>>(ei, E, n, flags, ssrc, sdst, ev, m);
  edge_exp<<<eb1, 256, 0, stream>>>(ei, E, n, flags, m, ev, denom);
  edge_aggr<64><<<eb4, 256, 0, stream>>>(ei, E, n, flags, ev, denom, A, B);
  finalize_gelu<64><<<nb64, 256, 0, stream>>>(B, b1, flags, n);

  // ---- Layer 2: 64 -> 64, GELU ----
  gemm_att<64, 64><<<gemm_blocks, 256, 0, stream>>>(B, 0, W2, as2, ad2, flags,
                                                    A, ssrc, sdst, n);
  init_layer<<<nb64, 256, 0, stream>>>(B, m, denom, n, 64);
  edge_score<<<eb1, 256, 0, stream>>>(ei, E, n, flags, ssrc, sdst, ev, m);
  edge_exp<<<eb1, 256, 0, stream>>>(ei, E, n, flags, m, ev, denom);
  edge_aggr<64><<<eb4, 256, 0, stream>>>(ei, E, n, flags, ev, denom, A, B);
  finalize_gelu<64><<<nb64, 256, 0, stream>>>(B, b2, flags, n);

  // ---- Layer 3: 64 -> 40, no activation ----
  gemm_att<64, 40><<<gemm_blocks, 256, 0, stream>>>(B, 0, W3, as3, ad3, flags,
                                                    A, ssrc, sdst, n);
  init_layer<<<nb64, 256, 0, stream>>>(B, m, denom, n, 40);
  edge_score<<<eb1, 256, 0, stream>>>(ei, E, n, flags, ssrc, sdst, ev, m);
  edge_exp<<<eb1, 256, 0, stream>>>(ei, E, n, flags, m, ev, denom);
  edge_aggr<40><<<eb4, 256, 0, stream>>>(ei, E, n, flags, ev, denom, A, B);
  finalize_out<40><<<nb40, 256, 0, stream>>>(B, b3, flags, d_out, n);
}